// Round 8
// baseline (303.413 us; speedup 1.0000x reference)
//
#include <hip/hip_runtime.h>
#include <stdint.h>

// ---------------------------------------------------------------------------
// kWTA: threshold = K-th largest of N fp32; out[i] = in[i] < thr ? 0 : in[i]
//
// Insight chain (measured across rounds):
//  - r2: in-kernel grid fusion w/ device fences = 3x slower (L2 wb/inv storms)
//  - r4: 4096-bin LDS histogram latency-bound on same-address atomics -> drop
//  - r5: fused zero-store+filter at 25% HBM: latency-bound
//  - r6: filter takes 98us even when input is L3-resident -> NOT BW-bound;
//        loads serialized (atomics in loop body block load hoisting)
//  - r7: register stash didn't fix it: VGPR=48 (can't hold 8 float4s) and 32
//        per-element branches fragment the loop into tiny basic blocks ->
//        scheduler can't clause loads. FIX: branchless body (key-max tree),
//        ONE rarely-taken branch per 4-vector group, direct atomic push in
//        the rare path, launch_bounds(256,8) for 32 waves/CU.
//
// Fast path (validated at runtime, exact):
//   memset(out, 0)  -- fill-rate dense zero (rocclr fill ~85% peak, measured)
//   K1: pure-read filter: 4 uint4 loads -> branchless keys -> umax tree ->
//       one branch; hits (key >= f2key(3.5), ~7.8k of 33.5M) atomic-push
//       (key,idx) to list A
//   K2: fallback gather-ALL into list B -- early-exits when list A valid
//   K3: single-block 8x4-bit radix select over full 32-bit keys -> exact
//       threshold; scatter-write winners (key >= thr) into zeroed output
// Fallback path (nA < K or list-A overflow; never for benchmark data):
// list B holds ALL N (key,idx) pairs (512 MiB ws suffices), same select.
// ---------------------------------------------------------------------------

// f2key(3.5f) = 0xC0600000
#define FILTER_KEY 0xC0600000u

// ctrl word offsets (ws[0..15])
//  ctrl[0] = list-A counter, ctrl[3] = threshold bits (debug),
//  ctrl[7] = list-B counter

typedef uint32_t u32x4 __attribute__((ext_vector_type(4)));

__device__ __forceinline__ uint32_t f2key(float x) {
  uint32_t u = __float_as_uint(x);
  return (u & 0x80000000u) ? ~u : (u | 0x80000000u);  // larger key <=> larger float
}
__device__ __forceinline__ float key2f(uint32_t k) {
  uint32_t u = (k & 0x80000000u) ? (k & 0x7fffffffu) : ~k;
  return __uint_as_float(u);
}
// branchless order-preserving key: u ^ (asr31(u) | 0x80000000)
__device__ __forceinline__ uint32_t bkey(uint32_t u) {
  return u ^ ((uint32_t)((int32_t)u >> 31) | 0x80000000u);
}
__device__ __forceinline__ u32x4 bkey4(u32x4 u) {
  u32x4 r;
  r.x = bkey(u.x); r.y = bkey(u.y); r.z = bkey(u.z); r.w = bkey(u.w);
  return r;
}
__device__ __forceinline__ uint32_t umax4_h(u32x4 a) {
  uint32_t m0 = a.x > a.y ? a.x : a.y;
  uint32_t m1 = a.z > a.w ? a.z : a.w;
  return m0 > m1 ? m0 : m1;
}

__device__ __forceinline__ void push1(uint32_t kk, uint32_t idx,
                                      uint32_t* ctrl, uint32_t* keysA,
                                      uint32_t* idxsA, uint32_t capA) {
  uint32_t p = atomicAdd(&ctrl[0], 1u);
  if (p < capA) { keysA[p] = kk; idxsA[p] = idx; }
}

// K1: pure-read candidate filter; branchless hot path, one branch per group.
__global__ void __launch_bounds__(256, 8) k_filter(
    const u32x4* __restrict__ in, int n4, int ntail,
    const float* __restrict__ in_s, uint32_t* __restrict__ ctrl,
    uint32_t* __restrict__ keysA, uint32_t* __restrict__ idxsA,
    uint32_t capA) {
  int gsz = gridDim.x * blockDim.x;
  int i = blockIdx.x * blockDim.x + threadIdx.x;

#define PUSH4(kv, base)                                                     \
  {                                                                         \
    if ((kv).x >= FILTER_KEY) push1((kv).x, (base) + 0u, ctrl, keysA, idxsA, capA); \
    if ((kv).y >= FILTER_KEY) push1((kv).y, (base) + 1u, ctrl, keysA, idxsA, capA); \
    if ((kv).z >= FILTER_KEY) push1((kv).z, (base) + 2u, ctrl, keysA, idxsA, capA); \
    if ((kv).w >= FILTER_KEY) push1((kv).w, (base) + 3u, ctrl, keysA, idxsA, capA); \
  }

  for (; i + 3 * gsz < n4; i += 4 * gsz) {
    // 4 independent coalesced 16B loads -- single basic block up to the one
    // group-level branch, so they issue as a clause
    u32x4 a = in[i];
    u32x4 b = in[i + gsz];
    u32x4 c = in[i + 2 * gsz];
    u32x4 d = in[i + 3 * gsz];
    u32x4 ka = bkey4(a), kb = bkey4(b), kc = bkey4(c), kd = bkey4(d);
    uint32_t ma = umax4_h(ka), mb = umax4_h(kb);
    uint32_t mc = umax4_h(kc), md = umax4_h(kd);
    uint32_t m0 = ma > mb ? ma : mb;
    uint32_t m1 = mc > md ? mc : md;
    uint32_t mm = m0 > m1 ? m0 : m1;
    if (mm >= FILTER_KEY) {  // ~20% of wave-iterations; exec-masked body
      PUSH4(ka, 4u * (uint32_t)i)
      PUSH4(kb, 4u * (uint32_t)(i + gsz))
      PUSH4(kc, 4u * (uint32_t)(i + 2 * gsz))
      PUSH4(kd, 4u * (uint32_t)(i + 3 * gsz))
    }
  }
  for (; i < n4; i += gsz) {  // remainder float4s
    u32x4 a = in[i];
    u32x4 ka = bkey4(a);
    if (umax4_h(ka) >= FILTER_KEY) PUSH4(ka, 4u * (uint32_t)i)
  }
#undef PUSH4
  if (blockIdx.x == 0 && (int)threadIdx.x < ntail) {  // scalar tail (n % 4)
    int j = n4 * 4 + threadIdx.x;
    uint32_t kk = f2key(in_s[j]);
    if (kk >= FILTER_KEY) push1(kk, (uint32_t)j, ctrl, keysA, idxsA, capA);
  }
}

// K2: fallback — gather ALL (key,idx) into list B. Early-exits on the fast
// path (nA >= K and list A not overflowed). Never triggers for N(0,1) data;
// keeps the kernel exact for arbitrary inputs.
__global__ void __launch_bounds__(256) k_gather_all(
    const float4* __restrict__ in, int n4, int ntail,
    const float* __restrict__ in_s, const int* __restrict__ kptr,
    uint32_t* __restrict__ ctrl, uint32_t* __restrict__ keysB,
    uint32_t* __restrict__ idxsB, uint32_t capA, uint32_t capB) {
  uint32_t K = (uint32_t)kptr[0];
  uint32_t nA = ctrl[0];
  if (nA >= K && nA <= capA) return;  // fast path: dispatch-cost only
  int stride = gridDim.x * blockDim.x;
  for (int i = blockIdx.x * blockDim.x + threadIdx.x; i < n4; i += stride) {
    float4 v = in[i];
    uint32_t kk[4] = {f2key(v.x), f2key(v.y), f2key(v.z), f2key(v.w)};
    uint32_t p = atomicAdd(&ctrl[7], 4u);
    for (int c = 0; c < 4; c++)
      if (p + c < capB) { keysB[p + c] = kk[c]; idxsB[p + c] = 4u * (uint32_t)i + c; }
  }
  if (blockIdx.x == 0 && (int)threadIdx.x < ntail) {
    int j = n4 * 4 + threadIdx.x;
    uint32_t p = atomicAdd(&ctrl[7], 1u);
    if (p < capB) { keysB[p] = f2key(in_s[j]); idxsB[p] = (uint32_t)j; }
  }
}

// K3: exact radix select over the full 32-bit keys (8 rounds x 4 bits) of
// the candidate list, then scatter-write winners into the zeroed output.
__global__ void __launch_bounds__(1024) k_final(
    const int* __restrict__ kptr, uint32_t* __restrict__ ctrl,
    const uint32_t* __restrict__ keysA, const uint32_t* __restrict__ idxsA,
    uint32_t capA, const uint32_t* __restrict__ keysB,
    const uint32_t* __restrict__ idxsB, uint32_t capB,
    float* __restrict__ out_s) {
  __shared__ uint32_t sh[16384];
  __shared__ uint32_t cnt[16];
  __shared__ uint32_t s_p, s_want;
  int t = threadIdx.x;
  uint32_t K = (uint32_t)kptr[0];
  uint32_t nA = ctrl[0];
  bool useA = (nA >= K) && (nA <= capA);
  const uint32_t* keys = useA ? keysA : keysB;
  const uint32_t* idxs = useA ? idxsA : idxsB;
  uint32_t n = useA ? nA : ctrl[7];
  if (!useA && n > capB) n = capB;
  bool useLds = (n <= 16384);
  if (useLds) for (uint32_t i = t; i < n; i += blockDim.x) sh[i] = keys[i];
  if (t == 0) { s_p = 0u; s_want = K; }
  __syncthreads();
  uint32_t p = s_p;
  for (int d = 7; d >= 0; d--) {
    if (t < 16) cnt[t] = 0;
    __syncthreads();
    int sh_hi = 4 * d + 4;  // bits above current digit (32 on first round)
    uint32_t pref = (sh_hi < 32) ? (p >> sh_hi) : 0u;
    for (uint32_t i = t; i < n; i += blockDim.x) {
      uint32_t kk = useLds ? sh[i] : keys[i];
      uint32_t hi = (sh_hi < 32) ? (kk >> sh_hi) : 0u;
      if (hi == pref) atomicAdd(&cnt[(kk >> (4 * d)) & 15u], 1u);
    }
    __syncthreads();
    if (t == 0) {
      uint32_t want = s_want, acc = 0, v = 0;
      for (int x = 15; x >= 0; x--) {
        if (acc + cnt[x] >= want) { v = (uint32_t)x; break; }
        acc += cnt[x];
      }
      s_p = p | (v << (4 * d));
      s_want = want - acc;
    }
    __syncthreads();
    p = s_p;
  }
  if (t == 0) ctrl[3] = __float_as_uint(key2f(p));
  // scatter winners: candidates at or above the exact K-th-largest key
  // (ties at the threshold value are all kept, matching where(in<thr,0,in))
  for (uint32_t i = t; i < n; i += blockDim.x) {
    uint32_t kk = useLds ? sh[i] : keys[i];
    if (kk >= p) out_s[idxs[i]] = key2f(kk);
  }
}

extern "C" void kernel_launch(void* const* d_in, const int* in_sizes, int n_in,
                              void* d_out, int out_size, void* d_ws, size_t ws_size,
                              hipStream_t stream) {
  const float* in = (const float*)d_in[0];
  const int* kptr = (const int*)d_in[1];
  float* out = (float*)d_out;
  int n = in_sizes[0];
  int n4 = n >> 2;
  int ntail = n & 3;

  uint32_t* ws = (uint32_t*)d_ws;
  uint32_t* ctrl = ws;  // 16 words
  size_t ws_words = ws_size / 4;
  size_t avail = (ws_words > 16) ? (ws_words - 16) : 0;
  uint32_t capA = (uint32_t)((avail / 4 < (1u << 20)) ? avail / 4 : (1u << 20));
  uint32_t* keysA = ws + 16;
  uint32_t* idxsA = keysA + capA;
  size_t availB = avail - 2 * (size_t)capA;
  uint32_t capB = (uint32_t)(availB / 2);  // >= N with the 512 MiB workspace
  uint32_t* keysB = idxsA + capA;
  uint32_t* idxsB = keysB + capB;

  // zero only the 64-byte control block (ws is poisoned before each launch)
  hipMemsetAsync(d_ws, 0, 16 * sizeof(uint32_t), stream);
  // dense zero of the output at fill rate (~85% HBM peak, measured);
  // winners are scatter-written by K3
  hipMemsetAsync(d_out, 0, (size_t)out_size, stream);

  // 2048 blocks x 256 thr = 32 waves/CU (exact full residency);
  // launch_bounds(256,8) caps VGPR<=64 so occupancy is register-feasible
  k_filter<<<2048, 256, 0, stream>>>((const u32x4*)in, n4, ntail, in,
                                     ctrl, keysA, idxsA, capA);
  k_gather_all<<<2048, 256, 0, stream>>>((const float4*)in, n4, ntail, in,
                                         kptr, ctrl, keysB, idxsB, capA, capB);
  k_final<<<1, 1024, 0, stream>>>(kptr, ctrl, keysA, idxsA, capA,
                                  keysB, idxsB, capB, out);
}

// Round 9
// 301.673 us; speedup vs baseline: 1.0058x; 1.0058x over previous
//
#include <hip/hip_runtime.h>
#include <stdint.h>

// ---------------------------------------------------------------------------
// kWTA: threshold = K-th largest of N fp32; out[i] = in[i] < thr ? 0 : in[i]
//
// Insight chain (measured across rounds):
//  - r2: in-kernel grid fusion w/ device fences = 3x slower (L2 wb/inv storms)
//  - r4: 4096-bin LDS histogram latency-bound on same-address atomics -> drop
//  - r5/r6/r7/r8: three source-level shapes of the filter pass all land at
//        87-99us, independent of whether data is L3-resident -> pure load-
//        latency serialization. r8's VGPR_Count=20 is the proof: the AMDGPU
//        scheduler schedules for MINIMUM register pressure and keeps exactly
//        one 16B load in flight per wave (18 waves/CU x 16B / ~300ns ~= 685
//        GB/s == measured). Source-level restructuring cannot beat the
//        scheduler. FIX: inline-asm clause — 8x global_load_dwordx4 + vmcnt(0)
//        in ONE asm volatile block. 8KB/wave in flight -> BW-bound at any
//        occupancy (waitcnt inside the same asm => no reorder hazard).
//
// Fast path (validated at runtime, exact):
//   memset(out, 0)  -- fill-rate dense zero (rocclr fill ~85% peak, measured)
//   K1: pure-read filter, asm-clause 8-deep MLP; branchless keys + umax tree;
//       hits (key >= f2key(3.5), ~7.8k of 33.5M) atomic-push (key,idx) to A
//   K2: fallback gather-ALL into list B -- early-exits when list A valid
//   K3: single-block 8x4-bit radix select over full 32-bit keys -> exact
//       threshold; scatter-write winners (key >= thr) into zeroed output
// Fallback path (nA < K or list-A overflow; never for benchmark data):
// list B holds ALL N (key,idx) pairs (512 MiB ws suffices), same select.
// ---------------------------------------------------------------------------

// f2key(3.5f) = 0xC0600000
#define FILTER_KEY 0xC0600000u

// ctrl word offsets (ws[0..15])
//  ctrl[0] = list-A counter, ctrl[3] = threshold bits (debug),
//  ctrl[7] = list-B counter

typedef uint32_t u32x4 __attribute__((ext_vector_type(4)));

__device__ __forceinline__ uint32_t f2key(float x) {
  uint32_t u = __float_as_uint(x);
  return (u & 0x80000000u) ? ~u : (u | 0x80000000u);  // larger key <=> larger float
}
__device__ __forceinline__ float key2f(uint32_t k) {
  uint32_t u = (k & 0x80000000u) ? (k & 0x7fffffffu) : ~k;
  return __uint_as_float(u);
}
// branchless order-preserving key: u ^ (asr31(u) | 0x80000000)
__device__ __forceinline__ uint32_t bkey(uint32_t u) {
  return u ^ ((uint32_t)((int32_t)u >> 31) | 0x80000000u);
}
__device__ __forceinline__ u32x4 bkey4(u32x4 u) {
  u32x4 r;
  r.x = bkey(u.x); r.y = bkey(u.y); r.z = bkey(u.z); r.w = bkey(u.w);
  return r;
}
__device__ __forceinline__ uint32_t umax4_h(u32x4 a) {
  uint32_t m0 = a.x > a.y ? a.x : a.y;
  uint32_t m1 = a.z > a.w ? a.z : a.w;
  return m0 > m1 ? m0 : m1;
}

__device__ __forceinline__ void push1(uint32_t kk, uint32_t idx,
                                      uint32_t* ctrl, uint32_t* keysA,
                                      uint32_t* idxsA, uint32_t capA) {
  uint32_t p = atomicAdd(&ctrl[0], 1u);
  if (p < capA) { keysA[p] = kk; idxsA[p] = idx; }
}

// K1: pure-read candidate filter. The 8-deep load clause is forced with
// inline asm (the compiler's min-pressure scheduler otherwise serializes
// loads to 1-in-flight; measured r5-r8). s_waitcnt vmcnt(0) lives INSIDE the
// same asm statement, so consumers (which depend on the asm outputs) can
// never be scheduled before the data is ready.
__global__ void __launch_bounds__(256) k_filter(
    const uint32_t* __restrict__ in, int n4, int ntail,
    const float* __restrict__ in_s, uint32_t* __restrict__ ctrl,
    uint32_t* __restrict__ keysA, uint32_t* __restrict__ idxsA,
    uint32_t capA) {
  int gsz = gridDim.x * blockDim.x;
  int i = blockIdx.x * blockDim.x + threadIdx.x;

#define PUSH4(kv, base)                                                     \
  {                                                                         \
    if ((kv).x >= FILTER_KEY) push1((kv).x, (base) + 0u, ctrl, keysA, idxsA, capA); \
    if ((kv).y >= FILTER_KEY) push1((kv).y, (base) + 1u, ctrl, keysA, idxsA, capA); \
    if ((kv).z >= FILTER_KEY) push1((kv).z, (base) + 2u, ctrl, keysA, idxsA, capA); \
    if ((kv).w >= FILTER_KEY) push1((kv).w, (base) + 3u, ctrl, keysA, idxsA, capA); \
  }

  for (; i + 7 * gsz < n4; i += 8 * gsz) {
    uint32_t o0 = (uint32_t)i * 16u;
    uint32_t o1 = (uint32_t)(i + gsz) * 16u;
    uint32_t o2 = (uint32_t)(i + 2 * gsz) * 16u;
    uint32_t o3 = (uint32_t)(i + 3 * gsz) * 16u;
    uint32_t o4 = (uint32_t)(i + 4 * gsz) * 16u;
    uint32_t o5 = (uint32_t)(i + 5 * gsz) * 16u;
    uint32_t o6 = (uint32_t)(i + 6 * gsz) * 16u;
    uint32_t o7 = (uint32_t)(i + 7 * gsz) * 16u;
    u32x4 a0, a1, a2, a3, a4, a5, a6, a7;
    asm volatile(
        "global_load_dwordx4 %[d0], %[o0], %[p]\n\t"
        "global_load_dwordx4 %[d1], %[o1], %[p]\n\t"
        "global_load_dwordx4 %[d2], %[o2], %[p]\n\t"
        "global_load_dwordx4 %[d3], %[o3], %[p]\n\t"
        "global_load_dwordx4 %[d4], %[o4], %[p]\n\t"
        "global_load_dwordx4 %[d5], %[o5], %[p]\n\t"
        "global_load_dwordx4 %[d6], %[o6], %[p]\n\t"
        "global_load_dwordx4 %[d7], %[o7], %[p]\n\t"
        "s_waitcnt vmcnt(0)"
        : [d0] "=&v"(a0), [d1] "=&v"(a1), [d2] "=&v"(a2), [d3] "=&v"(a3),
          [d4] "=&v"(a4), [d5] "=&v"(a5), [d6] "=&v"(a6), [d7] "=&v"(a7)
        : [o0] "v"(o0), [o1] "v"(o1), [o2] "v"(o2), [o3] "v"(o3),
          [o4] "v"(o4), [o5] "v"(o5), [o6] "v"(o6), [o7] "v"(o7),
          [p] "s"(in));
    u32x4 k0 = bkey4(a0), k1 = bkey4(a1), k2 = bkey4(a2), k3 = bkey4(a3);
    u32x4 k4 = bkey4(a4), k5 = bkey4(a5), k6 = bkey4(a6), k7 = bkey4(a7);
    uint32_t m0 = umax4_h(k0), m1 = umax4_h(k1), m2 = umax4_h(k2),
             m3 = umax4_h(k3), m4 = umax4_h(k4), m5 = umax4_h(k5),
             m6 = umax4_h(k6), m7 = umax4_h(k7);
    uint32_t x0 = m0 > m1 ? m0 : m1, x1 = m2 > m3 ? m2 : m3;
    uint32_t x2 = m4 > m5 ? m4 : m5, x3 = m6 > m7 ? m6 : m7;
    uint32_t y0 = x0 > x1 ? x0 : x1, y1 = x2 > x3 ? x2 : x3;
    uint32_t mm = y0 > y1 ? y0 : y1;
    if (mm >= FILTER_KEY) {  // rare; exec-masked cold path
      PUSH4(k0, 4u * (uint32_t)i)
      PUSH4(k1, 4u * (uint32_t)(i + gsz))
      PUSH4(k2, 4u * (uint32_t)(i + 2 * gsz))
      PUSH4(k3, 4u * (uint32_t)(i + 3 * gsz))
      PUSH4(k4, 4u * (uint32_t)(i + 4 * gsz))
      PUSH4(k5, 4u * (uint32_t)(i + 5 * gsz))
      PUSH4(k6, 4u * (uint32_t)(i + 6 * gsz))
      PUSH4(k7, 4u * (uint32_t)(i + 7 * gsz))
    }
  }
  for (; i < n4; i += gsz) {  // remainder float4s
    u32x4 a = *(const u32x4*)&in[4 * (size_t)i];
    u32x4 ka = bkey4(a);
    if (umax4_h(ka) >= FILTER_KEY) PUSH4(ka, 4u * (uint32_t)i)
  }
#undef PUSH4
  if (blockIdx.x == 0 && (int)threadIdx.x < ntail) {  // scalar tail (n % 4)
    int j = n4 * 4 + threadIdx.x;
    uint32_t kk = f2key(in_s[j]);
    if (kk >= FILTER_KEY) push1(kk, (uint32_t)j, ctrl, keysA, idxsA, capA);
  }
}

// K2: fallback — gather ALL (key,idx) into list B. Early-exits on the fast
// path (nA >= K and list A not overflowed). Never triggers for N(0,1) data;
// keeps the kernel exact for arbitrary inputs.
__global__ void __launch_bounds__(256) k_gather_all(
    const float4* __restrict__ in, int n4, int ntail,
    const float* __restrict__ in_s, const int* __restrict__ kptr,
    uint32_t* __restrict__ ctrl, uint32_t* __restrict__ keysB,
    uint32_t* __restrict__ idxsB, uint32_t capA, uint32_t capB) {
  uint32_t K = (uint32_t)kptr[0];
  uint32_t nA = ctrl[0];
  if (nA >= K && nA <= capA) return;  // fast path: dispatch-cost only
  int stride = gridDim.x * blockDim.x;
  for (int i = blockIdx.x * blockDim.x + threadIdx.x; i < n4; i += stride) {
    float4 v = in[i];
    uint32_t kk[4] = {f2key(v.x), f2key(v.y), f2key(v.z), f2key(v.w)};
    uint32_t p = atomicAdd(&ctrl[7], 4u);
    for (int c = 0; c < 4; c++)
      if (p + c < capB) { keysB[p + c] = kk[c]; idxsB[p + c] = 4u * (uint32_t)i + c; }
  }
  if (blockIdx.x == 0 && (int)threadIdx.x < ntail) {
    int j = n4 * 4 + threadIdx.x;
    uint32_t p = atomicAdd(&ctrl[7], 1u);
    if (p < capB) { keysB[p] = f2key(in_s[j]); idxsB[p] = (uint32_t)j; }
  }
}

// K3: exact radix select over the full 32-bit keys (8 rounds x 4 bits) of
// the candidate list, then scatter-write winners into the zeroed output.
__global__ void __launch_bounds__(1024) k_final(
    const int* __restrict__ kptr, uint32_t* __restrict__ ctrl,
    const uint32_t* __restrict__ keysA, const uint32_t* __restrict__ idxsA,
    uint32_t capA, const uint32_t* __restrict__ keysB,
    const uint32_t* __restrict__ idxsB, uint32_t capB,
    float* __restrict__ out_s) {
  __shared__ uint32_t sh[16384];
  __shared__ uint32_t cnt[16];
  __shared__ uint32_t s_p, s_want;
  int t = threadIdx.x;
  uint32_t K = (uint32_t)kptr[0];
  uint32_t nA = ctrl[0];
  bool useA = (nA >= K) && (nA <= capA);
  const uint32_t* keys = useA ? keysA : keysB;
  const uint32_t* idxs = useA ? idxsA : idxsB;
  uint32_t n = useA ? nA : ctrl[7];
  if (!useA && n > capB) n = capB;
  bool useLds = (n <= 16384);
  if (useLds) for (uint32_t i = t; i < n; i += blockDim.x) sh[i] = keys[i];
  if (t == 0) { s_p = 0u; s_want = K; }
  __syncthreads();
  uint32_t p = s_p;
  for (int d = 7; d >= 0; d--) {
    if (t < 16) cnt[t] = 0;
    __syncthreads();
    int sh_hi = 4 * d + 4;  // bits above current digit (32 on first round)
    uint32_t pref = (sh_hi < 32) ? (p >> sh_hi) : 0u;
    for (uint32_t i = t; i < n; i += blockDim.x) {
      uint32_t kk = useLds ? sh[i] : keys[i];
      uint32_t hi = (sh_hi < 32) ? (kk >> sh_hi) : 0u;
      if (hi == pref) atomicAdd(&cnt[(kk >> (4 * d)) & 15u], 1u);
    }
    __syncthreads();
    if (t == 0) {
      uint32_t want = s_want, acc = 0, v = 0;
      for (int x = 15; x >= 0; x--) {
        if (acc + cnt[x] >= want) { v = (uint32_t)x; break; }
        acc += cnt[x];
      }
      s_p = p | (v << (4 * d));
      s_want = want - acc;
    }
    __syncthreads();
    p = s_p;
  }
  if (t == 0) ctrl[3] = __float_as_uint(key2f(p));
  // scatter winners: candidates at or above the exact K-th-largest key
  // (ties at the threshold value are all kept, matching where(in<thr,0,in))
  for (uint32_t i = t; i < n; i += blockDim.x) {
    uint32_t kk = useLds ? sh[i] : keys[i];
    if (kk >= p) out_s[idxs[i]] = key2f(kk);
  }
}

extern "C" void kernel_launch(void* const* d_in, const int* in_sizes, int n_in,
                              void* d_out, int out_size, void* d_ws, size_t ws_size,
                              hipStream_t stream) {
  const float* in = (const float*)d_in[0];
  const int* kptr = (const int*)d_in[1];
  float* out = (float*)d_out;
  int n = in_sizes[0];
  int n4 = n >> 2;
  int ntail = n & 3;

  uint32_t* ws = (uint32_t*)d_ws;
  uint32_t* ctrl = ws;  // 16 words
  size_t ws_words = ws_size / 4;
  size_t avail = (ws_words > 16) ? (ws_words - 16) : 0;
  uint32_t capA = (uint32_t)((avail / 4 < (1u << 20)) ? avail / 4 : (1u << 20));
  uint32_t* keysA = ws + 16;
  uint32_t* idxsA = keysA + capA;
  size_t availB = avail - 2 * (size_t)capA;
  uint32_t capB = (uint32_t)(availB / 2);  // >= N with the 512 MiB workspace
  uint32_t* keysB = idxsA + capA;
  uint32_t* idxsB = keysB + capB;

  // zero only the 64-byte control block (ws is poisoned before each launch)
  hipMemsetAsync(d_ws, 0, 16 * sizeof(uint32_t), stream);
  // dense zero of the output at fill rate (~85% HBM peak, measured);
  // winners are scatter-written by K3
  hipMemsetAsync(d_out, 0, (size_t)out_size, stream);

  k_filter<<<2048, 256, 0, stream>>>((const uint32_t*)in, n4, ntail, in,
                                     ctrl, keysA, idxsA, capA);
  k_gather_all<<<2048, 256, 0, stream>>>((const float4*)in, n4, ntail, in,
                                         kptr, ctrl, keysB, idxsB, capA, capB);
  k_final<<<1, 1024, 0, stream>>>(kptr, ctrl, keysA, idxsA, capA,
                                  keysB, idxsB, capB, out);
}